// Round 2
// baseline (172.432 us; speedup 1.0000x reference)
//
#include <hip/hip_runtime.h>

// mean(|box5(x)-box5(y)|) = mean(|box5(x-y)|); separable 5x5 box, pad=4.
// B=64, H=W=512, out 516x516. Wave-autonomous: each wave = (img, 12-row strip).
// Lane owns 8 contiguous columns (2x float4 per array per row). Vertical
// rolling sum in registers (fully unrolled ring -> no dynamic reg indexing).
// Horizontal 5-tap in-register with 4-wide halo via __shfl_up. No barriers
// in the hot loop. Finalize fused via last-block counter.

#define TR      12
#define STRIPS  43              // 43*12 = 516
#define NWAVES  (64 * STRIPS)   // 2752
#define NBLOCKS (NWAVES / 4)    // 688

__global__ __launch_bounds__(256) void box_loss_kernel(
    const float* __restrict__ x, const float* __restrict__ y,
    float* __restrict__ ws, float* __restrict__ out)
{
    __shared__ float wsum[4];

    const int lane  = threadIdx.x & 63;
    const int wid   = (blockIdx.x << 2) + (threadIdx.x >> 6);
    const int img   = wid / STRIPS;
    const int strip = wid - img * STRIPS;
    const int i0    = strip * TR;

    const size_t base = (size_t)img * (512 * 512) + (size_t)(lane * 8);
    const float* xb = x + base;
    const float* yb = y + base;

    float hist[5][8];
    float v[8];
    #pragma unroll
    for (int j = 0; j < 8; ++j) v[j] = 0.f;
    #pragma unroll
    for (int s = 0; s < 5; ++s)
        #pragma unroll
        for (int j = 0; j < 8; ++j) hist[s][j] = 0.f;

    float acc = 0.f;

    #pragma unroll
    for (int k = 0; k < TR + 4; ++k) {
        const int r  = i0 - 4 + k;                 // input row
        const int rc = min(max(r, 0), 511);        // clamped (always loadable)
        const bool valid = (r == rc);
        const float* xr = xb + (size_t)rc * 512;
        const float* yr = yb + (size_t)rc * 512;
        float4 xa = ((const float4*)xr)[0];
        float4 xc = ((const float4*)xr)[1];
        float4 ya = ((const float4*)yr)[0];
        float4 yc = ((const float4*)yr)[1];

        float d[8];
        d[0] = xa.x - ya.x; d[1] = xa.y - ya.y; d[2] = xa.z - ya.z; d[3] = xa.w - ya.w;
        d[4] = xc.x - yc.x; d[5] = xc.y - yc.y; d[6] = xc.z - yc.z; d[7] = xc.w - yc.w;
        #pragma unroll
        for (int j = 0; j < 8; ++j) d[j] = valid ? d[j] : 0.f;

        const int slot = k % 5;                    // compile-time under unroll
        #pragma unroll
        for (int j = 0; j < 8; ++j) {
            v[j] += d[j] - hist[slot][j];
            hist[slot][j] = d[j];
        }

        if (k >= 4) {                              // output row i = i0 + (k-4)
            // halo: prev lane's v[4..7] = columns c0-4..c0-1
            float h0 = __shfl_up(v[4], 1, 64);
            float h1 = __shfl_up(v[5], 1, 64);
            float h2 = __shfl_up(v[6], 1, 64);
            float h3 = __shfl_up(v[7], 1, 64);
            if (lane == 0) { h0 = 0.f; h1 = 0.f; h2 = 0.f; h3 = 0.f; }

            float s = h0 + h1 + h2 + h3 + v[0];    // out col c0
            acc += fabsf(s);
            s += v[1] - h0;  acc += fabsf(s);
            s += v[2] - h1;  acc += fabsf(s);
            s += v[3] - h2;  acc += fabsf(s);
            s += v[4] - h3;  acc += fabsf(s);
            s += v[5] - v[0]; acc += fabsf(s);
            s += v[6] - v[1]; acc += fabsf(s);
            s += v[7] - v[2]; acc += fabsf(s);
            if (lane == 63) {                      // out cols 512..515 (right pad)
                float t = v[7];  acc += fabsf(t);  // |v511|
                t += v[6];       acc += fabsf(t);  // |v510+v511|
                t += v[5];       acc += fabsf(t);
                t += v[4];       acc += fabsf(t);
            }
        }
    }

    // wave reduce (64 lanes)
    #pragma unroll
    for (int off = 32; off > 0; off >>= 1)
        acc += __shfl_down(acc, off, 64);
    if (lane == 0) wsum[threadIdx.x >> 6] = acc;
    __syncthreads();

    if (threadIdx.x == 0) {
        float s = wsum[0] + wsum[1] + wsum[2] + wsum[3];
        atomicAdd(ws, s);
        __threadfence();
        unsigned* cnt = (unsigned*)(ws + 1);
        unsigned done = atomicAdd(cnt, 1u);
        if (done == (unsigned)(gridDim.x - 1)) {
            float total = atomicAdd(ws, 0.0f);     // coherent read of final sum
            out[0] = total * (1.0f / (25.0f * 64.0f * 516.0f * 516.0f));
        }
    }
}

extern "C" void kernel_launch(void* const* d_in, const int* in_sizes, int n_in,
                              void* d_out, int out_size, void* d_ws, size_t ws_size,
                              hipStream_t stream) {
    const float* x = (const float*)d_in[0];
    const float* y = (const float*)d_in[1];
    float* out = (float*)d_out;
    float* ws  = (float*)d_ws;

    hipMemsetAsync(ws, 0, 8, stream);   // ws[0]=sum, ws[1]=block counter

    box_loss_kernel<<<NBLOCKS, 256, 0, stream>>>(x, y, ws, out);
}